// Round 6
// baseline (107.880 us; speedup 1.0000x reference)
//
#include <hip/hip_runtime.h>
#include <hip/hip_bf16.h>

#define BHN 32      // B*H
#define SEQ 4096
#define DIM 128
#define TROWS 64               // rows per LDS tile
#define CH 16                  // chunks per head (fixed this round)

typedef __bf16 bf16x8 __attribute__((ext_vector_type(8)));
typedef __bf16 bf16x4 __attribute__((ext_vector_type(4)));
typedef float  f32x4  __attribute__((ext_vector_type(4)));

__device__ __forceinline__ bf16x8 cvt8(const float* f) {
    bf16x8 r;
#pragma unroll
    for (int i = 0; i < 8; ++i) r[i] = (__bf16)f[i];
    return r;
}

// ---------------------------------------------------------------------------
// Phase 1 (8-wave): partial kv^T + FUSED last-block reduction.
//   C[e][d] = sum_s v[s][e]*k[s][d]
//
// R5 POST-MORTEM: 5 structural variants (occ 32/44/66%, prefetch on/off,
// vmcnt-drain on/off) all land 48-56us profiled / ~68us bench -> p1 is at
// ITS service ceiling (~2.9 TB/s touch) for this access mix. Scheduling
// levers exhausted. Whole-problem arithmetic: 3-kernel decomposition moves
// ~360 MB -> ~57us structural floor at 6.3 TB/s; we're at 67.6. Remaining
// slack = the reduce dispatch + stream serialization (all 512 p1 blocks ->
// reduce -> p2).
//
// R6: SPLIT-K TAIL FUSION. After storing its partial slab, each block
// increments a per-head device-scope counter (ACQ_REL); the CH-th arriver
// acquire-fences and reduces all CH slabs -> swizzled bf16 ws2. 31/32 heads'
// reduces overlap other heads' main loops; only the last head's (~1-2us)
// is on the critical path. Removes the p1_reduce dispatch entirely.
// Coherence (G16, cross-XCD): release = __syncthreads (per-thread vmcnt
// drain, stores in L2) + ACQ_REL agent RMW (wbL2); acquire = agent fence
// in the last block before reading other XCDs' slabs.
//
// p1 body = R5's pipelined version (neutral vs R0, kept as-is).
// LDS swizzle: elem (d,s) at d*64 + (((s>>3) ^ key(d))*8) + (s&7),
//   key(d) = (d&7) ^ ((d>>2)&7)  -> <=2-way on both write and read lanes.
// ---------------------------------------------------------------------------
__global__ __launch_bounds__(512) void p1_kv(const float* __restrict__ kin,
                                             const float* __restrict__ vin,
                                             __bf16* __restrict__ ws1,
                                             __bf16* __restrict__ ws2,
                                             int* __restrict__ cnt) {
    constexpr int SR = SEQ / CH;       // rows per block (256)
    constexpr int NT = SR / TROWS;     // tiles per block (4)

    __shared__ __align__(16) __bf16 kt[2][DIM][TROWS];  // 32 KB
    __shared__ __align__(16) __bf16 vt[2][DIM][TROWS];  // 32 KB

    const int bh    = blockIdx.x / CH;
    const int chunk = blockIdx.x % CH;
    const int tid = threadIdx.x;

    const int dcol = tid & 31;     // d-quad index 0..31  -> d0 = dcol*4
    const int sgrp = tid >> 5;     // s-quad index 0..15  -> s0 = sgrp*4
    const int d0 = dcol * 4;
    const int s0 = sgrp * 4;

    const int w = tid >> 6;
    const int l = tid & 63;
    const int g = l >> 4;
    const int c = l & 15;

    const float* kb = kin + (size_t)bh * SEQ * DIM + (size_t)chunk * SR * DIM;
    const float* vb = vin + (size_t)bh * SEQ * DIM + (size_t)chunk * SR * DIM;

    f32x4 acc[8];
#pragma unroll
    for (int nt = 0; nt < 8; ++nt) acc[nt] = (f32x4){0.f, 0.f, 0.f, 0.f};

    // single set of staging regs; refilled for t+1 right after pack(t)
    f32x4 kr[4], vr[4];
    {   // prologue: tile 0
        const size_t off = (size_t)s0 * DIM + d0;
#pragma unroll
        for (int j = 0; j < 4; ++j) {
            kr[j] = *(const f32x4*)(kb + off + j * DIM);
            vr[j] = *(const f32x4*)(vb + off + j * DIM);
        }
    }

#pragma unroll
    for (int t = 0; t < NT; ++t) {
        const int p = t & 1;   // compile-time after full unroll

        // ---- pack current tile (waits vmcnt for its loads internally)
#pragma unroll
        for (int jd = 0; jd < 4; ++jd) {
            const int dd  = d0 + jd;
            const int key = (dd & 7) ^ ((dd >> 2) & 7);
            const int o   = (((sgrp >> 1) ^ key) * 8) + (sgrp & 1) * 4;
            bf16x4 pk, pv;
#pragma unroll
            for (int j = 0; j < 4; ++j) {
                pk[j] = (__bf16)kr[j][jd];
                pv[j] = (__bf16)vr[j][jd];
            }
            *(bf16x4*)&kt[p][dd][o] = pk;
            *(bf16x4*)&vt[p][dd][o] = pv;
        }

        // ---- prefetch tile t+1 into the just-freed regs; fences pin it here
        __builtin_amdgcn_sched_barrier(0);
        if (t + 1 < NT) {
            const size_t off = ((size_t)((t + 1) * TROWS + s0)) * DIM + d0;
#pragma unroll
            for (int j = 0; j < 4; ++j) {
                kr[j] = *(const f32x4*)(kb + off + j * DIM);
                vr[j] = *(const f32x4*)(vb + off + j * DIM);
            }
        }
        __builtin_amdgcn_sched_barrier(0);

        // ---- producer handoff WITHOUT vmcnt drain: my ds_writes done, then
        //      block-wide barrier. Prefetch loads stay in flight.
        asm volatile("s_waitcnt lgkmcnt(0)" ::: "memory");
        __builtin_amdgcn_s_barrier();

        // ---- MFMA: wave w owns e-strip [w*16,+16); K-dim 64 s (2 steps)
        const int e    = w * 16 + c;
        const int keyE = (e & 7) ^ ((e >> 2) & 7);
#pragma unroll
        for (int st = 0; st < 2; ++st) {
            bf16x8 af = *(const bf16x8*)&vt[p][e][((st * 4 + g) ^ keyE) * 8];
#pragma unroll
            for (int nt = 0; nt < 8; ++nt) {
                const int d    = nt * 16 + c;
                const int keyD = (d & 7) ^ ((d >> 2) & 7);
                bf16x8 bfr = *(const bf16x8*)&kt[p][d][((st * 4 + g) ^ keyD) * 8];
                acc[nt] = __builtin_amdgcn_mfma_f32_16x16x32_bf16(af, bfr, acc[nt], 0, 0, 0);
            }
        }
        // no trailing barrier: next pack writes buffer p^1 (safe, see R5)
    }

    // ---- store bf16 partials, MFMA-native flat layout: f = nt*2048 + tid*4 + r
    __bf16* outp = ws1 + ((size_t)chunk * BHN + bh) * (DIM * DIM);
#pragma unroll
    for (int nt = 0; nt < 8; ++nt) {
        bf16x4 pq;
#pragma unroll
        for (int r = 0; r < 4; ++r) pq[r] = (__bf16)acc[nt][r];
        *(bf16x4*)(outp + nt * 2048 + tid * 4) = pq;
    }

    // ---- split-K tail: last block of this head reduces all CH slabs -----
    __syncthreads();   // drains each thread's vmcnt -> all stores in L2
    __shared__ int sLast;
    if (tid == 0) {
        // ACQ_REL agent RMW: release flushes this XCD's L2 (our block's
        // stores) before the increment becomes visible.
        int prev = __hip_atomic_fetch_add(&cnt[bh], 1, __ATOMIC_ACQ_REL,
                                          __HIP_MEMORY_SCOPE_AGENT);
        sLast = (prev == CH - 1);
    }
    __syncthreads();
    if (sLast) {
        // acquire: invalidate stale L1/L2 lines before reading slabs
        // written by blocks on other XCDs (and by previous iterations).
        __builtin_amdgcn_fence(__ATOMIC_ACQUIRE, "agent");

        const __bf16* hb = ws1 + (size_t)bh * (DIM * DIM);
        __bf16* dst = ws2 + (size_t)bh * (DIM * DIM);
        // decode of flat layout f = nt*2048 + tidw*4 + r, tidw = wv*64+gg*16+cc:
        //   nt=f>>11; wv=(f>>8)&7; gg=(f>>6)&3; cc=(f>>2)&15; r=f&3
        //   e = wv*16 + gg*4 + r ;  d = nt*16 + cc
        // p2 swizzle: (e,d) at e*128 + ((d>>3)^(e&15))*8 + (d&7)
#pragma unroll
        for (int rep = 0; rep < 4; ++rep) {
            const int r11 = rep * 512 + tid;       // consecutive tid -> 16B stride
            const __bf16* base = hb + r11 * 8;
            float s[8] = {0.f, 0.f, 0.f, 0.f, 0.f, 0.f, 0.f, 0.f};
#pragma unroll
            for (int ch = 0; ch < CH; ++ch) {
                bf16x8 a = *(const bf16x8*)(base + (size_t)ch * BHN * DIM * DIM);
#pragma unroll
                for (int i = 0; i < 8; ++i) s[i] += (float)a[i];
            }
#pragma unroll
            for (int i = 0; i < 8; ++i) {
                const int f  = r11 * 8 + i;
                const int nt = f >> 11;
                const int wv = (f >> 8) & 7;
                const int gg = (f >> 6) & 3;
                const int cc = (f >> 2) & 15;
                const int r  = f & 3;
                const int e  = wv * 16 + gg * 4 + r;
                const int d  = nt * 16 + cc;
                dst[e * DIM + (((d >> 3) ^ (e & 15)) * 8) + (d & 7)] = (__bf16)s[i];
            }
        }
    }
}

// ---------------------------------------------------------------------------
// Phase 2 (flipped operands): out[s][e] = v[s][e] + sum_d q[s][d] * kv[d][e]
// Compute C[e][s] = mfma(A = kv_frag (M=e), B = q_frag (N=s)).
// Each lane holds 4 CONSECUTIVE e per fragment -> f32x4 epilogue.
// grid = 32 heads * 32 row-chunks = 1024 blocks, 512 threads (8 waves).
// UNCHANGED: VGPR=32 -> 4 blocks/CU; real (non-profiled) rate ~ copy roofline.
// ---------------------------------------------------------------------------
__global__ __launch_bounds__(512) void p2_qkv(const float* __restrict__ qin,
                                              const float* __restrict__ vin,
                                              const __bf16* __restrict__ ws2,
                                              float* __restrict__ outp) {
    __shared__ __align__(16) __bf16 kvs[DIM * DIM];

    const int bh = blockIdx.x & 31;
    const int rc = blockIdx.x >> 5;
    const int tid = threadIdx.x;

    {   // linear 16B-copy of the (already swizzled) 32 KB head slab into LDS
        const uint4* src = (const uint4*)(ws2 + (size_t)bh * DIM * DIM);
        uint4* dst = (uint4*)kvs;
#pragma unroll
        for (int j = 0; j < 4; ++j) dst[tid + j * 512] = src[tid + j * 512];
    }
    __syncthreads();

    const int w = tid >> 6;
    const int l = tid & 63;
    const int g = l >> 4;
    const int c = l & 15;
    const int s = rc * 128 + w * 16 + c;     // this lane's output row

    // hoist all 4 Q fragments: B[d][s], lane holds q[s][ks*32 + g*8 .. +8)
    const float* qrow = qin + (size_t)bh * SEQ * DIM + (size_t)s * DIM + g * 8;
    bf16x8 bq[4];
#pragma unroll
    for (int ks = 0; ks < 4; ++ks) {
        f32x4 x = *(const f32x4*)(qrow + ks * 32);
        f32x4 y = *(const f32x4*)(qrow + ks * 32 + 4);
        float tmp[8];
        tmp[0]=x[0]; tmp[1]=x[1]; tmp[2]=x[2]; tmp[3]=x[3];
        tmp[4]=y[0]; tmp[5]=y[1]; tmp[6]=y[2]; tmp[7]=y[3];
        bq[ks] = cvt8(tmp);
    }

    f32x4 acc[8];
#pragma unroll
    for (int et = 0; et < 8; ++et) acc[et] = (f32x4){0.f, 0.f, 0.f, 0.f};

#pragma unroll
    for (int ks = 0; ks < 4; ++ks) {
#pragma unroll
        for (int et = 0; et < 8; ++et) {
            const int e = et * 16 + c;                 // A's M index = lane&15
            const int slot = (ks * 4 + g) ^ c;         // unswizzle: d-slice = ks*32+g*8
            bf16x8 a = *(const bf16x8*)&kvs[e * DIM + slot * 8];
            acc[et] = __builtin_amdgcn_mfma_f32_16x16x32_bf16(a, bq[ks], acc[et], 0, 0, 0);
        }
    }

    // epilogue: lane holds out[s][et*16 + g*4 .. +4) -> vectorized V add + store
    const float* vb = vin + (size_t)bh * SEQ * DIM;
    float* ob = outp + (size_t)bh * SEQ * DIM;
#pragma unroll
    for (int et = 0; et < 8; ++et) {
        const size_t idx = (size_t)s * DIM + et * 16 + g * 4;
        f32x4 vv = *(const f32x4*)(vb + idx);
        f32x4 o = acc[et] + vv;
        *(f32x4*)(ob + idx) = o;
    }
}

// ---------------------------------------------------------------------------
// Workspace layout:
//   ws2  = d_ws + 0                     (1 MiB reduced kv, swizzled bf16)
//   ws1  = d_ws + 1 MiB                 (CH x 1 MiB bf16 partials)
//   cnt  = d_ws + 17 MiB                (32 x int, zeroed per launch)
// hipMemsetAsync is stream-ordered and graph-capture-legal (the harness's
// own reset() uses it); it also re-zeroes after workspace re-poisoning.
// ---------------------------------------------------------------------------
extern "C" void kernel_launch(void* const* d_in, const int* in_sizes, int n_in,
                              void* d_out, int out_size, void* d_ws, size_t ws_size,
                              hipStream_t stream) {
    const float* q = (const float*)d_in[0];
    const float* k = (const float*)d_in[1];
    const float* v = (const float*)d_in[2];
    float* out = (float*)d_out;

    const size_t slab = (size_t)BHN * DIM * DIM * sizeof(__bf16);  // 1 MiB
    __bf16* ws2 = (__bf16*)d_ws;
    __bf16* ws1 = (__bf16*)((char*)d_ws + slab);
    int*    cnt = (int*)((char*)d_ws + slab * (1 + CH));

    hipMemsetAsync(cnt, 0, BHN * sizeof(int), stream);
    p1_kv<<<BHN * CH, 512, 0, stream>>>(k, v, ws1, ws2, cnt);
    p2_qkv<<<BHN * (SEQ / 128), 512, 0, stream>>>(q, v, ws2, out);
}

// Round 7
// 67.935 us; speedup vs baseline: 1.5880x; 1.5880x over previous
//
#include <hip/hip_runtime.h>
#include <hip/hip_bf16.h>

#define BHN 32      // B*H
#define SEQ 4096
#define DIM 128
#define CHUNKS 16
#define SROWS (SEQ / CHUNKS)   // 256 rows per phase-1 block
#define TROWS 64               // rows per LDS tile
#define NTILE (SROWS / TROWS)  // 4 tiles per block

typedef __bf16 bf16x8 __attribute__((ext_vector_type(8)));
typedef __bf16 bf16x4 __attribute__((ext_vector_type(4)));
typedef float  f32x4  __attribute__((ext_vector_type(4)));

__device__ __forceinline__ bf16x8 cvt8(const float* f) {
    bf16x8 r;
#pragma unroll
    for (int i = 0; i < 8; ++i) r[i] = (__bf16)f[i];
    return r;
}

// ---------------------------------------------------------------------------
// Phase 1 (low-VGPR, 8-wave): partial kv^T. C[e][d] = sum_s v[s][e]*k[s][d]
// grid = 32 heads * 16 chunks = 512 blocks, 512 threads (8 waves).
//
// SESSION VERDICT (R0-R6): this exact configuration is the measured best
// (67.6us bench). Levers tried and falsified:
//   - occupancy 32/44/66% (CH=32, reg-shaving, launch_bounds): all neutral
//     or worse; launch_bounds(512,8) spilled (+60MB scratch FETCH, +18us).
//   - reg prefetch + LDS dbuf + lgkmcnt-only barrier (R5): neutral.
//   - interleaved chunk->tile mapping (R3): -14% (L2-fill amplification).
//   - split-K tail fusion w/ agent atomics (R6): -58% (per-block agent
//     release = L2 wb, acquire fence = L2 inv; evicts k/v for all).
// Whole-pipeline sustained rate = ~368MB/67.6us = 5.4 TB/s = 86% of the
// 6.3 TB/s copy ceiling -> memory-roofline-bound; profiled per-dispatch
// rates (~2.9 TB/s) are rocprof serialization artifacts.
//
// LDS 32 KB (kt/vt [128][64] bf16) -> 3 blocks/CU capacity.
// LDS swizzle: elem (d,s) at d*64 + (((s>>3) ^ key(d))*8) + (s&7),
//   key(d) = (d&7) ^ ((d>>2)&7)   -- bijective mod 8 BOTH on consecutive d
//   (read lanes span c) and on stride-4 d (write lanes span dcol) -> <=2-way.
// Staging: per instr a wave reads 2 x 512 B full rows (perfect coalescing).
// ---------------------------------------------------------------------------
__global__ __launch_bounds__(512) void p1_kv(const float* __restrict__ kin,
                                             const float* __restrict__ vin,
                                             __bf16* __restrict__ ws1) {
    __shared__ __align__(16) __bf16 kt[DIM][TROWS];  // 16 KB
    __shared__ __align__(16) __bf16 vt[DIM][TROWS];  // 16 KB

    const int bh    = blockIdx.x >> 4;
    const int chunk = blockIdx.x & 15;
    const int tid = threadIdx.x;

    const int dcol = tid & 31;     // d-quad index 0..31  -> d0 = dcol*4
    const int sgrp = tid >> 5;     // s-quad index 0..15  -> s0 = sgrp*4
    const int d0 = dcol * 4;
    const int s0 = sgrp * 4;

    const int w = tid >> 6;
    const int l = tid & 63;
    const int g = l >> 4;
    const int c = l & 15;

    const float* kb = kin + (size_t)bh * SEQ * DIM + (size_t)chunk * SROWS * DIM;
    const float* vb = vin + (size_t)bh * SEQ * DIM + (size_t)chunk * SROWS * DIM;

    f32x4 acc[8];
#pragma unroll
    for (int nt = 0; nt < 8; ++nt) acc[nt] = (f32x4){0.f, 0.f, 0.f, 0.f};

    for (int t = 0; t < NTILE; ++t) {
        // ---- load 4 rows x 16B-of-d per thread (wave: 2 full 512B rows/instr)
        const float* kp = kb + (size_t)(t * TROWS + s0) * DIM + d0;
        const float* vp = vb + (size_t)(t * TROWS + s0) * DIM + d0;
        f32x4 kr[4], vr[4];
#pragma unroll
        for (int j = 0; j < 4; ++j) {
            kr[j] = *(const f32x4*)(kp + j * DIM);
            vr[j] = *(const f32x4*)(vp + j * DIM);
        }
        // ---- transpose-pack into swizzled LDS (bf16x4 of 4 s per d-row)
#pragma unroll
        for (int jd = 0; jd < 4; ++jd) {
            const int dd  = d0 + jd;
            const int key = (dd & 7) ^ ((dd >> 2) & 7);
            const int off = (((sgrp >> 1) ^ key) * 8) + (sgrp & 1) * 4;
            bf16x4 pk, pv;
#pragma unroll
            for (int j = 0; j < 4; ++j) {
                pk[j] = (__bf16)kr[j][jd];
                pv[j] = (__bf16)vr[j][jd];
            }
            *(bf16x4*)&kt[dd][off] = pk;
            *(bf16x4*)&vt[dd][off] = pv;
        }
        __syncthreads();

        // ---- MFMA: wave w owns e-strip [w*16, w*16+16); K-dim 64 s (2 steps)
        const int e    = w * 16 + c;
        const int keyE = (e & 7) ^ ((e >> 2) & 7);
#pragma unroll
        for (int st = 0; st < 2; ++st) {
            bf16x8 af = *(const bf16x8*)&vt[e][((st * 4 + g) ^ keyE) * 8];
#pragma unroll
            for (int nt = 0; nt < 8; ++nt) {
                const int d    = nt * 16 + c;
                const int keyD = (d & 7) ^ ((d >> 2) & 7);
                bf16x8 bfr = *(const bf16x8*)&kt[d][((st * 4 + g) ^ keyD) * 8];
                acc[nt] = __builtin_amdgcn_mfma_f32_16x16x32_bf16(af, bfr, acc[nt], 0, 0, 0);
            }
        }
        __syncthreads();
    }

    // store bf16 partials, MFMA-native flat layout: f = nt*2048 + tid*4 + r
    // (each bf16x4 store instr = 512B/wave contiguous burst)
    __bf16* outp = ws1 + ((size_t)chunk * BHN + bh) * (DIM * DIM);
#pragma unroll
    for (int nt = 0; nt < 8; ++nt) {
        bf16x4 p;
#pragma unroll
        for (int r = 0; r < 4; ++r) p[r] = (__bf16)acc[nt][r];
        *(bf16x4*)(outp + nt * 2048 + tid * 4) = p;
    }
}

// ---------------------------------------------------------------------------
// Phase 1.5: reduce 16 bf16 partials (fp32 accum) -> bf16 kv^T swizzled for p2:
//   element (e,d) at  e*128 + ((d>>3)^(e&15))*8 + (d&7)
// Decode of p1's flat layout  f = nt*2048 + tid*4 + r, tid = w*64+g*16+c:
//   nt=f>>11; w=(f>>8)&7; g=(f>>6)&3; c=(f>>2)&15; r=f&3
//   e = w*16 + g*4 + r ;  d = nt*16 + c
// 256 blocks * 256 threads; thread owns 8 consecutive f (16B loads/chunk).
// ---------------------------------------------------------------------------
__global__ __launch_bounds__(256) void p1_reduce(const __bf16* __restrict__ ws1,
                                                 __bf16* __restrict__ ws2) {
    const int t   = blockIdx.x * 256 + threadIdx.x;  // 65536 threads
    const int bh  = t >> 11;
    const int r11 = t & 2047;

    const __bf16* base = ws1 + (size_t)bh * (DIM * DIM) + r11 * 8;
    float s[8] = {0.f, 0.f, 0.f, 0.f, 0.f, 0.f, 0.f, 0.f};
#pragma unroll
    for (int ch = 0; ch < CHUNKS; ++ch) {
        bf16x8 a = *(const bf16x8*)(base + (size_t)ch * BHN * DIM * DIM);
#pragma unroll
        for (int i = 0; i < 8; ++i) s[i] += (float)a[i];
    }

    __bf16* dst = ws2 + (size_t)bh * (DIM * DIM);
#pragma unroll
    for (int i = 0; i < 8; ++i) {
        const int f  = r11 * 8 + i;
        const int nt = f >> 11;
        const int wv = (f >> 8) & 7;
        const int gg = (f >> 6) & 3;
        const int cc = (f >> 2) & 15;
        const int r  = f & 3;
        const int e  = wv * 16 + gg * 4 + r;
        const int d  = nt * 16 + cc;
        dst[e * DIM + (((d >> 3) ^ (e & 15)) * 8) + (d & 7)] = (__bf16)s[i];
    }
}

// ---------------------------------------------------------------------------
// Phase 2 (flipped operands): out[s][e] = v[s][e] + sum_d q[s][d] * kv[d][e]
// Compute C[e][s] = mfma(A = kv_frag (M=e), B = q_frag (N=s)).
// Each lane holds 4 CONSECUTIVE e per fragment -> f32x4 epilogue.
// grid = 32 heads * 32 row-chunks = 1024 blocks, 512 threads (8 waves).
// ---------------------------------------------------------------------------
__global__ __launch_bounds__(512) void p2_qkv(const float* __restrict__ qin,
                                              const float* __restrict__ vin,
                                              const __bf16* __restrict__ ws2,
                                              float* __restrict__ outp) {
    __shared__ __align__(16) __bf16 kvs[DIM * DIM];

    const int bh = blockIdx.x & 31;
    const int rc = blockIdx.x >> 5;
    const int tid = threadIdx.x;

    {   // linear 16B-copy of the (already swizzled) 32 KB head slab into LDS
        const uint4* src = (const uint4*)(ws2 + (size_t)bh * DIM * DIM);
        uint4* dst = (uint4*)kvs;
#pragma unroll
        for (int j = 0; j < 4; ++j) dst[tid + j * 512] = src[tid + j * 512];
    }
    __syncthreads();

    const int w = tid >> 6;
    const int l = tid & 63;
    const int g = l >> 4;
    const int c = l & 15;
    const int s = rc * 128 + w * 16 + c;     // this lane's output row

    // hoist all 4 Q fragments: B[d][s], lane holds q[s][ks*32 + g*8 .. +8)
    const float* qrow = qin + (size_t)bh * SEQ * DIM + (size_t)s * DIM + g * 8;
    bf16x8 bq[4];
#pragma unroll
    for (int ks = 0; ks < 4; ++ks) {
        f32x4 x = *(const f32x4*)(qrow + ks * 32);
        f32x4 y = *(const f32x4*)(qrow + ks * 32 + 4);
        float tmp[8];
        tmp[0]=x[0]; tmp[1]=x[1]; tmp[2]=x[2]; tmp[3]=x[3];
        tmp[4]=y[0]; tmp[5]=y[1]; tmp[6]=y[2]; tmp[7]=y[3];
        bq[ks] = cvt8(tmp);
    }

    f32x4 acc[8];
#pragma unroll
    for (int et = 0; et < 8; ++et) acc[et] = (f32x4){0.f, 0.f, 0.f, 0.f};

#pragma unroll
    for (int ks = 0; ks < 4; ++ks) {
#pragma unroll
        for (int et = 0; et < 8; ++et) {
            const int e = et * 16 + c;                 // A's M index = lane&15
            const int slot = (ks * 4 + g) ^ c;         // unswizzle: d-slice = ks*32+g*8
            bf16x8 a = *(const bf16x8*)&kvs[e * DIM + slot * 8];
            acc[et] = __builtin_amdgcn_mfma_f32_16x16x32_bf16(a, bq[ks], acc[et], 0, 0, 0);
        }
    }

    // epilogue: lane holds out[s][et*16 + g*4 .. +4) -> vectorized V add + store
    const float* vb = vin + (size_t)bh * SEQ * DIM;
    float* ob = outp + (size_t)bh * SEQ * DIM;
#pragma unroll
    for (int et = 0; et < 8; ++et) {
        const size_t idx = (size_t)s * DIM + et * 16 + g * 4;
        f32x4 vv = *(const f32x4*)(vb + idx);
        f32x4 o = acc[et] + vv;
        *(f32x4*)(ob + idx) = o;
    }
}

// ---------------------------------------------------------------------------
extern "C" void kernel_launch(void* const* d_in, const int* in_sizes, int n_in,
                              void* d_out, int out_size, void* d_ws, size_t ws_size,
                              hipStream_t stream) {
    const float* q = (const float*)d_in[0];
    const float* k = (const float*)d_in[1];
    const float* v = (const float*)d_in[2];
    float* out = (float*)d_out;

    __bf16* ws1 = (__bf16*)d_ws;                                       // 16 MiB bf16 partials
    __bf16* ws2 = (__bf16*)((char*)d_ws + (size_t)CHUNKS * BHN * DIM * DIM * 2);

    p1_kv<<<BHN * CHUNKS, 512, 0, stream>>>(k, v, ws1);
    p1_reduce<<<(BHN * DIM * DIM / 8) / 256, 256, 0, stream>>>(ws1, ws2);
    p2_qkv<<<BHN * (SEQ / 128), 512, 0, stream>>>(q, v, ws2, out);
}

// Round 8
// 66.115 us; speedup vs baseline: 1.6317x; 1.0275x over previous
//
#include <hip/hip_runtime.h>
#include <hip/hip_bf16.h>

#define BHN 32      // B*H
#define SEQ 4096
#define DIM 128
#define CHUNKS 8
#define SROWS (SEQ / CHUNKS)   // 512 rows per phase-1 block
#define TROWS 64               // rows per LDS tile
#define NTILE (SROWS / TROWS)  // 8 tiles per block

typedef __bf16 bf16x8 __attribute__((ext_vector_type(8)));
typedef __bf16 bf16x4 __attribute__((ext_vector_type(4)));
typedef float  f32x4  __attribute__((ext_vector_type(4)));

__device__ __forceinline__ bf16x8 cvt8(const float* f) {
    bf16x8 r;
#pragma unroll
    for (int i = 0; i < 8; ++i) r[i] = (__bf16)f[i];
    return r;
}

// ---------------------------------------------------------------------------
// Phase 1 (8-wave, PIPELINED): partial kv^T. C[e][d] = sum_s v[s][e]*k[s][d]
// grid = 32 heads * 8 chunks = 256 blocks (1 block/CU).
//
// R8 RATIONALE: last untried traffic lever. CHUNKS 16->8 halves the partial
// round-trip (32->16 MB total, ~2.5us at ceiling) and halves p1_reduce.
// Known risk: 1 block/CU -> zero memory demand during pack/MFMA UNLESS the
// next tile's loads are already in flight. That is exactly what R5's
// verified pipeline provides (reg prefetch pinned by sched_barrier fences,
// LDS double-buffer, lgkmcnt-only barrier so no vmcnt drain kills the
// prefetch). At 2 blocks/CU this machinery was redundant (R5 neutral);
// at 1 block/CU it is the only coverage -- first config where it has a job.
//
// Session ledger (R0-R7): occupancy 32/44/66% all neutral; launch_bounds
// clamp spilled (+18us); interleaved chunk map -14%; agent-atomic tail
// fusion -58%; best = R0 structure @ 67.6-67.9us = 86% of copy ceiling.
//
// LDS 64 KB (kt/vt[2][128][64] bf16) -> fits easily at 1 block/CU.
// LDS swizzle: elem (d,s) at d*64 + (((s>>3) ^ key(d))*8) + (s&7),
//   key(d) = (d&7) ^ ((d>>2)&7)   -- bijective mod 8 BOTH on consecutive d
//   (read lanes span c) and on stride-4 d (write lanes span dcol) -> <=2-way.
// Staging: per instr a wave reads 2 x 512 B full rows (perfect coalescing).
// ---------------------------------------------------------------------------
__global__ __launch_bounds__(512) void p1_kv(const float* __restrict__ kin,
                                             const float* __restrict__ vin,
                                             __bf16* __restrict__ ws1) {
    __shared__ __align__(16) __bf16 kt[2][DIM][TROWS];  // 32 KB
    __shared__ __align__(16) __bf16 vt[2][DIM][TROWS];  // 32 KB

    const int bh    = blockIdx.x >> 3;
    const int chunk = blockIdx.x & 7;
    const int tid = threadIdx.x;

    const int dcol = tid & 31;     // d-quad index 0..31  -> d0 = dcol*4
    const int sgrp = tid >> 5;     // s-quad index 0..15  -> s0 = sgrp*4
    const int d0 = dcol * 4;
    const int s0 = sgrp * 4;

    const int w = tid >> 6;
    const int l = tid & 63;
    const int g = l >> 4;
    const int c = l & 15;

    const float* kb = kin + (size_t)bh * SEQ * DIM + (size_t)chunk * SROWS * DIM;
    const float* vb = vin + (size_t)bh * SEQ * DIM + (size_t)chunk * SROWS * DIM;

    f32x4 acc[8];
#pragma unroll
    for (int nt = 0; nt < 8; ++nt) acc[nt] = (f32x4){0.f, 0.f, 0.f, 0.f};

    // single set of staging regs; refilled for t+1 right after pack(t)
    f32x4 kr[4], vr[4];
    {   // prologue: tile 0
        const size_t off = (size_t)s0 * DIM + d0;
#pragma unroll
        for (int j = 0; j < 4; ++j) {
            kr[j] = *(const f32x4*)(kb + off + j * DIM);
            vr[j] = *(const f32x4*)(vb + off + j * DIM);
        }
    }

#pragma unroll
    for (int t = 0; t < NTILE; ++t) {
        const int p = t & 1;   // compile-time after full unroll

        // ---- pack current tile (compiler waits vmcnt for its loads)
#pragma unroll
        for (int jd = 0; jd < 4; ++jd) {
            const int dd  = d0 + jd;
            const int key = (dd & 7) ^ ((dd >> 2) & 7);
            const int o   = (((sgrp >> 1) ^ key) * 8) + (sgrp & 1) * 4;
            bf16x4 pk, pv;
#pragma unroll
            for (int j = 0; j < 4; ++j) {
                pk[j] = (__bf16)kr[j][jd];
                pv[j] = (__bf16)vr[j][jd];
            }
            *(bf16x4*)&kt[p][dd][o] = pk;
            *(bf16x4*)&vt[p][dd][o] = pv;
        }

        // ---- prefetch tile t+1 into the just-freed regs; fences pin it here
        // (R3 lesson: unfenced prefetch is silently sunk to its consumer)
        __builtin_amdgcn_sched_barrier(0);
        if (t + 1 < NTILE) {
            const size_t off = ((size_t)((t + 1) * TROWS + s0)) * DIM + d0;
#pragma unroll
            for (int j = 0; j < 4; ++j) {
                kr[j] = *(const f32x4*)(kb + off + j * DIM);
                vr[j] = *(const f32x4*)(vb + off + j * DIM);
            }
        }
        __builtin_amdgcn_sched_barrier(0);

        // ---- producer handoff WITHOUT vmcnt drain: my ds_writes done, then
        //      block-wide barrier. Prefetch loads stay in flight across MFMA.
        asm volatile("s_waitcnt lgkmcnt(0)" ::: "memory");
        __builtin_amdgcn_s_barrier();

        // ---- MFMA: wave w owns e-strip [w*16,+16); K-dim 64 s (2 steps)
        const int e    = w * 16 + c;
        const int keyE = (e & 7) ^ ((e >> 2) & 7);
#pragma unroll
        for (int st = 0; st < 2; ++st) {
            bf16x8 af = *(const bf16x8*)&vt[p][e][((st * 4 + g) ^ keyE) * 8];
#pragma unroll
            for (int nt = 0; nt < 8; ++nt) {
                const int d    = nt * 16 + c;
                const int keyD = (d & 7) ^ ((d >> 2) & 7);
                bf16x8 bfr = *(const bf16x8*)&kt[p][d][((st * 4 + g) ^ keyD) * 8];
                acc[nt] = __builtin_amdgcn_mfma_f32_16x16x32_bf16(af, bfr, acc[nt], 0, 0, 0);
            }
        }
        // no trailing barrier: next pack writes buffer p^1. A wave reaches
        // pack of buffer p again only after the NEXT barrier, by which time
        // every wave has retired its MFMA(t) LDS reads (program order:
        // MFMA(t) -> pack(t+1) -> barrier(t+1)). Verified in R5/R6 runs.
    }

    // store bf16 partials, MFMA-native flat layout: f = nt*2048 + tid*4 + r
    // (each bf16x4 store instr = 512B/wave contiguous burst)
    __bf16* outp = ws1 + ((size_t)chunk * BHN + bh) * (DIM * DIM);
#pragma unroll
    for (int nt = 0; nt < 8; ++nt) {
        bf16x4 pq;
#pragma unroll
        for (int r = 0; r < 4; ++r) pq[r] = (__bf16)acc[nt][r];
        *(bf16x4*)(outp + nt * 2048 + tid * 4) = pq;
    }
}

// ---------------------------------------------------------------------------
// Phase 1.5: reduce 8 bf16 partials (fp32 accum) -> bf16 kv^T swizzled for p2:
//   element (e,d) at  e*128 + ((d>>3)^(e&15))*8 + (d&7)
// Decode of p1's flat layout  f = nt*2048 + tid*4 + r, tid = w*64+g*16+c:
//   nt=f>>11; w=(f>>8)&7; g=(f>>6)&3; c=(f>>2)&15; r=f&3
//   e = w*16 + g*4 + r ;  d = nt*16 + c
// 256 blocks * 256 threads; thread owns 8 consecutive f (16B loads/chunk).
// ---------------------------------------------------------------------------
__global__ __launch_bounds__(256) void p1_reduce(const __bf16* __restrict__ ws1,
                                                 __bf16* __restrict__ ws2) {
    const int t   = blockIdx.x * 256 + threadIdx.x;  // 65536 threads
    const int bh  = t >> 11;
    const int r11 = t & 2047;

    const __bf16* base = ws1 + (size_t)bh * (DIM * DIM) + r11 * 8;
    float s[8] = {0.f, 0.f, 0.f, 0.f, 0.f, 0.f, 0.f, 0.f};
#pragma unroll
    for (int ch = 0; ch < CHUNKS; ++ch) {
        bf16x8 a = *(const bf16x8*)(base + (size_t)ch * BHN * DIM * DIM);
#pragma unroll
        for (int i = 0; i < 8; ++i) s[i] += (float)a[i];
    }

    __bf16* dst = ws2 + (size_t)bh * (DIM * DIM);
#pragma unroll
    for (int i = 0; i < 8; ++i) {
        const int f  = r11 * 8 + i;
        const int nt = f >> 11;
        const int wv = (f >> 8) & 7;
        const int gg = (f >> 6) & 3;
        const int cc = (f >> 2) & 15;
        const int r  = f & 3;
        const int e  = wv * 16 + gg * 4 + r;
        const int d  = nt * 16 + cc;
        dst[e * DIM + (((d >> 3) ^ (e & 15)) * 8) + (d & 7)] = (__bf16)s[i];
    }
}

// ---------------------------------------------------------------------------
// Phase 2 (flipped operands): out[s][e] = v[s][e] + sum_d q[s][d] * kv[d][e]
// Compute C[e][s] = mfma(A = kv_frag (M=e), B = q_frag (N=s)).
// Each lane holds 4 CONSECUTIVE e per fragment -> f32x4 epilogue.
// grid = 32 heads * 32 row-chunks = 1024 blocks, 512 threads (8 waves).
// UNCHANGED all session: near its streaming floor (~192 MB / ~30us real).
// ---------------------------------------------------------------------------
__global__ __launch_bounds__(512) void p2_qkv(const float* __restrict__ qin,
                                              const float* __restrict__ vin,
                                              const __bf16* __restrict__ ws2,
                                              float* __restrict__ outp) {
    __shared__ __align__(16) __bf16 kvs[DIM * DIM];

    const int bh = blockIdx.x & 31;
    const int rc = blockIdx.x >> 5;
    const int tid = threadIdx.x;

    {   // linear 16B-copy of the (already swizzled) 32 KB head slab into LDS
        const uint4* src = (const uint4*)(ws2 + (size_t)bh * DIM * DIM);
        uint4* dst = (uint4*)kvs;
#pragma unroll
        for (int j = 0; j < 4; ++j) dst[tid + j * 512] = src[tid + j * 512];
    }
    __syncthreads();

    const int w = tid >> 6;
    const int l = tid & 63;
    const int g = l >> 4;
    const int c = l & 15;
    const int s = rc * 128 + w * 16 + c;     // this lane's output row

    // hoist all 4 Q fragments: B[d][s], lane holds q[s][ks*32 + g*8 .. +8)
    const float* qrow = qin + (size_t)bh * SEQ * DIM + (size_t)s * DIM + g * 8;
    bf16x8 bq[4];
#pragma unroll
    for (int ks = 0; ks < 4; ++ks) {
        f32x4 x = *(const f32x4*)(qrow + ks * 32);
        f32x4 y = *(const f32x4*)(qrow + ks * 32 + 4);
        float tmp[8];
        tmp[0]=x[0]; tmp[1]=x[1]; tmp[2]=x[2]; tmp[3]=x[3];
        tmp[4]=y[0]; tmp[5]=y[1]; tmp[6]=y[2]; tmp[7]=y[3];
        bq[ks] = cvt8(tmp);
    }

    f32x4 acc[8];
#pragma unroll
    for (int et = 0; et < 8; ++et) acc[et] = (f32x4){0.f, 0.f, 0.f, 0.f};

#pragma unroll
    for (int ks = 0; ks < 4; ++ks) {
#pragma unroll
        for (int et = 0; et < 8; ++et) {
            const int e = et * 16 + c;                 // A's M index = lane&15
            const int slot = (ks * 4 + g) ^ c;         // unswizzle: d-slice = ks*32+g*8
            bf16x8 a = *(const bf16x8*)&kvs[e * DIM + slot * 8];
            acc[et] = __builtin_amdgcn_mfma_f32_16x16x32_bf16(a, bq[ks], acc[et], 0, 0, 0);
        }
    }

    // epilogue: lane holds out[s][et*16 + g*4 .. +4) -> vectorized V add + store
    const float* vb = vin + (size_t)bh * SEQ * DIM;
    float* ob = outp + (size_t)bh * SEQ * DIM;
#pragma unroll
    for (int et = 0; et < 8; ++et) {
        const size_t idx = (size_t)s * DIM + et * 16 + g * 4;
        f32x4 vv = *(const f32x4*)(vb + idx);
        f32x4 o = acc[et] + vv;
        *(f32x4*)(ob + idx) = o;
    }
}

// ---------------------------------------------------------------------------
// Workspace: ws1 (8 x 1 MiB bf16 partials) + ws2 (1 MiB reduced kv) = 9 MiB.
// ---------------------------------------------------------------------------
extern "C" void kernel_launch(void* const* d_in, const int* in_sizes, int n_in,
                              void* d_out, int out_size, void* d_ws, size_t ws_size,
                              hipStream_t stream) {
    const float* q = (const float*)d_in[0];
    const float* k = (const float*)d_in[1];
    const float* v = (const float*)d_in[2];
    float* out = (float*)d_out;

    __bf16* ws1 = (__bf16*)d_ws;                                   // 8 MiB partials
    __bf16* ws2 = (__bf16*)((char*)d_ws + (size_t)CHUNKS * BHN * DIM * DIM * 2);

    p1_kv<<<BHN * CHUNKS, 512, 0, stream>>>(k, v, ws1);
    p1_reduce<<<(BHN * DIM * DIM / 8) / 256, 256, 0, stream>>>(ws1, ws2);
    p2_qkv<<<BHN * (SEQ / 128), 512, 0, stream>>>(q, v, ws2, out);
}